// Round 9
// baseline (287.954 us; speedup 1.0000x reference)
//
#include <hip/hip_runtime.h>
#include <hip/hip_bf16.h>

namespace {
constexpr int BS = 32;
constexpr int NQ = 1000;
constexpr int NCLS = 100;
constexpr int TPS = 50;
constexpr int TT = BS * TPS;        // 1600
constexpr int NQALL = BS * NQ;      // 32000
constexpr int QTILE = 32;
constexpr int NTILES = 32;          // 32*32 = 1024 covers 1000 (tail tile = 8)
constexpr int NG = TT / 4;          // 400 target groups of 4
}

typedef float f32x4 __attribute__((ext_vector_type(4)));

static __device__ __forceinline__ float clamp01(float x) {
  return fminf(fmaxf(x, 0.0f), 1.0f);
}

// ---- Kernel 1 (fused): focal table (LDS) + cost C + ct transpose + row-min partials
// 1024 blocks (32 batches x 32 q-tiles), 38.6 KB LDS -> 4 blocks/CU, 16 waves/CU.
__global__ void __launch_bounds__(256) hm_cost(const float* __restrict__ logits,
                                               const float* __restrict__ pred_boxes,
                                               const int* __restrict__ tgt_ids,
                                               const float* __restrict__ tgt_bbox,
                                               float* __restrict__ C,
                                               float* __restrict__ ct,
                                               float* __restrict__ pmin,
                                               int* __restrict__ parg) {
  __shared__ float  s_tab[QTILE * NCLS];   // 12.8 KB focal table for this q-tile
  __shared__ float4 s_c2v[NG];             // 6.4 KB  target centers, packed by 4
  __shared__ float4 s_w2v[NG];             // 6.4 KB  target widths
  __shared__ int4   s_id4[NG];             // 6.4 KB  target class ids
  __shared__ float  s_tr[TPS][QTILE + 1];  // 6.6 KB  own-batch transpose staging

  const int bx = blockIdx.x;
  const int b = bx >> 5;
  const int tile = bx & 31;
  const int q0 = tile * QTILE;
  const int nq = min(QTILE, NQ - q0);      // 32 or 8 (tail)
  const int tid = threadIdx.x;
  const int tlo = b * TPS;

  // Phase A: focal class-cost table for queries [q0, q0+nq)
  for (int i = tid; i < nq * NCLS; i += 256) {
    int ql = i / NCLS, c = i - ql * NCLS;
    float x = logits[((size_t)(b * NQ + q0 + ql)) * NCLS + c];
    float p = 1.0f / (1.0f + expf(-x));
    float neg = 0.75f * (p * p) * (-logf(1.0f - p + 1e-8f));
    float pos = 0.25f * ((1.0f - p) * (1.0f - p)) * (-logf(p + 1e-8f));
    s_tab[i] = pos - neg;
  }
  // Phase B: stage targets (packed float4 groups)
  for (int t = tid; t < TT; t += 256) {
    ((float*)s_c2v)[t] = tgt_bbox[2 * t];
    ((float*)s_w2v)[t] = tgt_bbox[2 * t + 1];
    ((int*)s_id4)[t] = tgt_ids[t];
  }
  __syncthreads();

  // Phase C: static mapping — 32 rows x 8 lanes; each thread: 50 float4 groups.
  {
    const int ql = tid >> 3;               // 0..31
    const int l8 = tid & 7;
    if (ql < nq) {
      const int gq = b * NQ + q0 + ql;
      const float c1 = pred_boxes[2 * gq], w1 = pred_boxes[2 * gq + 1];
      const float s1 = clamp01(c1 - 0.5f * w1);
      const float e1 = clamp01(c1 + 0.5f * w1);
      const float len1 = e1 - s1;
      const float* tabrow = s_tab + ql * NCLS;
      float* crow = C + (size_t)gq * TT;
      #pragma unroll 2
      for (int k = 0; k < 50; ++k) {
        const int g = l8 + (k << 3);       // 0..399
        float4 c2 = s_c2v[g];
        float4 w2 = s_w2v[g];
        int4 id = s_id4[g];
        const float* c2p = &c2.x;
        const float* w2p = &w2.x;
        const int* idp = &id.x;
        f32x4 o;
        #pragma unroll
        for (int kk = 0; kk < 4; ++kk) {
          float C2 = c2p[kk], W2 = w2p[kk];
          float cb = fabsf(c1 - C2) + fabsf(w1 - W2);
          float S2 = clamp01(C2 - 0.5f * W2);
          float E2 = clamp01(C2 + 0.5f * W2);
          float inter = fmaxf(fminf(e1, E2) - fmaxf(s1, S2), 0.0f);
          float uni = (len1 + (E2 - S2)) - inter;
          float cg = -(inter * __builtin_amdgcn_rcpf(uni));
          o[kk] = (cb + tabrow[idp[kk]]) + cg;
        }
        __builtin_nontemporal_store(o, (f32x4*)(crow + 4 * g));  // streaming store
        int d = 4 * g - tlo;               // own-batch window capture
        if (d > -4 && d < TPS) {
          #pragma unroll
          for (int kk = 0; kk < 4; ++kk) {
            int tt = d + kk;
            if ((unsigned)tt < (unsigned)TPS) s_tr[tt][ql] = o[kk];
          }
        }
      }
    }
  }
  __syncthreads();

  // Phase D: coalesced write of transposed own-batch slice -> ct[b*50+t][q]
  for (int i2 = tid; i2 < TPS * nq; i2 += 256) {
    int ttt = i2 / nq, qq = i2 - ttt * nq;
    ct[(size_t)(tlo + ttt) * NQ + q0 + qq] = s_tr[ttt][qq];
  }
  // Phase E: per-tile row-min partials over s_tr (threads 0..49, serial over nq)
  if (tid < TPS) {
    float bv = 1e30f;
    int bj = 0x7fffffff;
    for (int qq = 0; qq < nq; ++qq) {
      float c = s_tr[tid][qq];
      if (c < bv) { bv = c; bj = q0 + qq + 1; }   // strict < keeps first index
    }
    pmin[(size_t)(tlo + tid) * NTILES + tile] = bv;
    parg[(size_t)(tlo + tid) * NTILES + tile] = bj;
  }
}

// ---- Kernel 2: warm-started Jonker-Volgenant, one wave per batch -------------
// Reduce 32 row-min partials/row, greedy admissible warm start (u[i]=row min,
// v=0, argmin claim), then exact JV phases for the ~1-2 unmatched rows.
// Optimal assignment is unique for continuous random costs -> matches reference.
__global__ void __launch_bounds__(64) hm_lsa(const float* __restrict__ ct,
                                             const float* __restrict__ pmin,
                                             const int* __restrict__ parg,
                                             float* __restrict__ out_idx) {
  __shared__ double u[TPS + 1];
  __shared__ int p[NQ + 1];
  __shared__ int way[NQ + 1];
  __shared__ int claim[NQ + 1];
  __shared__ int s_unm[TPS];
  __shared__ int s_nu;

  const double INFD = 1e18;
  int b = blockIdx.x;
  int lane = threadIdx.x;
  const float* cbase = ct + (size_t)b * TPS * NQ;

  double v[16], minv[16];
  #pragma unroll
  for (int k = 0; k < 16; ++k) v[k] = 0.0;
  for (int j = lane; j <= NQ; j += 64) { p[j] = 0; way[j] = 0; claim[j] = 0x7fffffff; }
  if (lane < TPS) u[lane + 1] = 0.0;
  if (lane == 63) u[0] = 0.0;
  __syncthreads();

  // reduce row-min partials (lane < 50: serial over 32 tile partials)
  int i_row = 0, myarg = 0;
  if (lane < TPS) {
    int r = b * TPS + lane;
    float bv = 1e30f;
    int bj = 0x7fffffff;
    #pragma unroll
    for (int t = 0; t < NTILES; ++t) {
      float c = pmin[(size_t)r * NTILES + t];
      int j = parg[(size_t)r * NTILES + t];
      if (c < bv || (c == bv && j < bj)) { bv = c; bj = j; }
    }
    i_row = lane + 1;
    myarg = bj;
    u[i_row] = (double)bv;
    atomicMin(&claim[myarg], i_row);
  }
  __syncthreads();
  bool matched = false;
  if (lane < TPS) matched = (claim[myarg] == i_row);
  if (matched) p[myarg] = i_row;
  bool un = (lane < TPS) && !matched;
  unsigned long long mk = __ballot(un);
  if (un) { int pos = __popcll(mk & ((1ull << lane) - 1ull)); s_unm[pos] = i_row; }
  if (lane == 0) s_nu = __popcll(mk);
  __syncthreads();
  int nu = s_nu;

  // exact JV augmenting phases for unmatched rows
  for (int ph = 0; ph < nu; ++ph) {
    int i = s_unm[ph];
    #pragma unroll
    for (int k = 0; k < 16; ++k) minv[k] = INFD;
    unsigned usedmask = 0u;
    if (lane == 0) p[0] = i;
    int j0 = 0;
    int jfin = 0;
    __syncthreads();
    while (true) {
      if (j0 > 0) {
        int kk = (j0 - 1) >> 6, ll = (j0 - 1) & 63;
        if (lane == ll) usedmask |= (1u << kk);
      }
      int i0 = p[j0];
      double ui0 = u[i0];
      const float* row = cbase + (size_t)(i0 - 1) * NQ;
      float rv[16];
      #pragma unroll
      for (int k = 0; k < 16; ++k) {
        int idx = lane + (k << 6); if (idx > NQ - 1) idx = NQ - 1;
        rv[k] = row[idx];
      }
      double bv = INFD; int bj = 0x7fffffff;
      #pragma unroll
      for (int k = 0; k < 16; ++k) {
        int j = 1 + lane + (k << 6);
        bool valid = (k < 15) | (lane < 40);
        if (valid && !((usedmask >> k) & 1u)) {
          double cur = ((double)rv[k] - ui0) - v[k];
          if (cur < minv[k]) { minv[k] = cur; way[j] = j0; }
          double mv = minv[k];
          if (mv < bv || (mv == bv && j < bj)) { bv = mv; bj = j; }
        }
      }
      #pragma unroll
      for (int off = 32; off; off >>= 1) {
        double ov = __shfl_xor(bv, off);
        int oj = __shfl_xor(bj, off);
        if (ov < bv || (ov == bv && oj < bj)) { bv = ov; bj = oj; }
      }
      double delta = bv;
      int j1 = bj;
      if (lane == 0) u[i] += delta;
      #pragma unroll
      for (int k = 0; k < 16; ++k) {
        int j = 1 + lane + (k << 6);
        bool valid = (k < 15) | (lane < 40);
        if (!valid) continue;
        if ((usedmask >> k) & 1u) {
          u[p[j]] += delta;            // distinct rows -> race-free
          v[k] -= delta;
        } else {
          minv[k] -= delta;
        }
      }
      __syncthreads();
      if (p[j1] == 0) { jfin = j1; break; }
      j0 = j1;
    }
    __syncthreads();
    if (lane == 0) {
      int j0a = jfin;
      while (j0a != 0) { int jn = way[j0a]; p[j0a] = p[jn]; j0a = jn; }
    }
    __syncthreads();
  }

  // extraction: ascending column order == identity argsort
  float* o = out_idx + b * 2 * TPS;
  int total = 0;
  #pragma unroll
  for (int k = 0; k < 16; ++k) {
    int j = 1 + lane + (k << 6);
    bool valid = (k < 15) | (lane < 40);
    int pj = valid ? p[j] : 0;
    bool m = valid && (pj != 0);
    unsigned long long mask = __ballot(m);
    int pos = total + __popcll(mask & ((1ull << lane) - 1ull));
    if (m) { o[pos] = (float)(j - 1); o[TPS + pos] = (float)(pj - 1); }
    total += __popcll(mask);
  }
}

extern "C" void kernel_launch(void* const* d_in, const int* in_sizes, int n_in,
                              void* d_out, int out_size, void* d_ws, size_t ws_size,
                              hipStream_t stream) {
  const float* logits     = (const float*)d_in[0];  // [32,1000,100]
  const float* pred_boxes = (const float*)d_in[1];  // [32,1000,2]
  const int*   tgt_ids    = (const int*)d_in[2];    // [1600]
  const float* tgt_bbox   = (const float*)d_in[3];  // [1600,2]
  float* out = (float*)d_out;                       // C (51.2M f32) then indices

  char* ws = (char*)d_ws;
  float* ct   = (float*)ws;                                  // 6.4 MB
  float* pmin = (float*)(ws + (size_t)TT * NQ * 4);          // 204.8 KB
  int*   parg = (int*)(ws + (size_t)TT * NQ * 4 + (size_t)TT * NTILES * 4);

  hm_cost<<<BS * NTILES, 256, 0, stream>>>(logits, pred_boxes, tgt_ids, tgt_bbox,
                                           out, ct, pmin, parg);
  hm_lsa<<<BS, 64, 0, stream>>>(ct, pmin, parg, out + (size_t)NQALL * TT);
}